// Round 24
// baseline (1472.384 us; speedup 1.0000x reference)
//
#include <hip/hip_runtime.h>
#include <hip/hip_bf16.h>

#define BB   16
#define NN   4096
#define DD   256
#define QS   768                    // fused qkv row stride
#define HH   4
#define DHH  64
#define MM   128
#define LL   4
#define NCC  32
#define COUT 10
#define BNQ  (BB*NN)                // 65536 rows
#define DNF  0.35355339059327373f   // 64^-0.25
#define RATIOF 0.08838834764831845f // 128^-0.5
#define FEPS 1e-4f

typedef __attribute__((ext_vector_type(8))) short bf16x8;
typedef __attribute__((ext_vector_type(4))) float f32x4;

// ---- bf16 helpers (raw ushort representation) ----
__device__ __forceinline__ float bf2f(unsigned short u) {
    return __uint_as_float(((unsigned)u) << 16);
}
__device__ __forceinline__ unsigned short f2bf(float x) {
    unsigned u = __float_as_uint(x);
    u += 0x7FFF + ((u >> 16) & 1);   // round-nearest-even
    return (unsigned short)(u >> 16);
}
// hardware packed f32x2 -> bf16x2 (RNE)
__device__ __forceinline__ unsigned cvtpk(float lo, float hi) {
    unsigned r;
    asm("v_cvt_pk_bf16_f32 %0, %1, %2" : "=v"(r) : "v"(lo), "v"(hi));
    return r;
}
__device__ __forceinline__ short4 pack4(float a, float b, float c, float d) {
    union { unsigned u[2]; short4 s; } x;
    x.u[0] = cvtpk(a, b);
    x.u[1] = cvtpk(c, d);
    return x.s;
}
__device__ __forceinline__ float4 ld4f(const float* p) { return *(const float4*)p; }
__device__ __forceinline__ float4 ld4f(const unsigned short* p) {
    ushort4 u = *(const ushort4*)p;
    return make_float4(bf2f(u.x), bf2f(u.y), bf2f(u.z), bf2f(u.w));
}
__device__ __forceinline__ void st4(float* p, float4 v) { *(float4*)p = v; }
__device__ __forceinline__ void st4(unsigned short* p, float4 v) {
    *(short4*)p = pack4(v.x, v.y, v.z, v.w);
}

// ---- monotone float<->uint encoding for atomicMax on floats ----
__device__ __forceinline__ unsigned fenc(float f) {
    unsigned u = __float_as_uint(f);
    return (u >> 31) ? ~u : (u | 0x80000000u);
}
__device__ __forceinline__ float fdec(unsigned e) {
    return __uint_as_float((e >> 31) ? (e ^ 0x80000000u) : ~e);
}

// ---- async global->LDS 16B copy (linear dest: wave-uniform base + lane*16) ----
#define GL2LDS(g, p) __builtin_amdgcn_global_load_lds( \
    (const __attribute__((address_space(1))) void*)(g), \
    (__attribute__((address_space(3))) void*)(p), 16, 0, 0)

// ---- MFMA fragment loaders ----
__device__ __forceinline__ bf16x8 ldfragL(const short* p) {
    short4 lo = *(const short4*)p;
    short4 hi = *(const short4*)(p + 16);
    bf16x8 f = {lo.x, lo.y, lo.z, lo.w, hi.x, hi.y, hi.z, hi.w};
    return f;
}
__device__ __forceinline__ bf16x8 ldfragG(const unsigned short* p) {
    ushort4 lo = *(const ushort4*)p;
    ushort4 hi = *(const ushort4*)(p + 16);
    bf16x8 f = {(short)lo.x, (short)lo.y, (short)lo.z, (short)lo.w,
                (short)hi.x, (short)hi.y, (short)hi.z, (short)hi.w};
    return f;
}
// C-tile pair -> B-fragment via packed converts
__device__ __forceinline__ bf16x8 pack8(f32x4 lo, f32x4 hi) {
    union { unsigned u[4]; bf16x8 v; } x;
    x.u[0] = cvtpk(lo[0], lo[1]);
    x.u[1] = cvtpk(lo[2], lo[3]);
    x.u[2] = cvtpk(hi[0], hi[1]);
    x.u[3] = cvtpk(hi[2], hi[3]);
    return x.v;
}
#define MFMA(a, b, c) __builtin_amdgcn_mfma_f32_16x16x32_bf16((a), (b), (c), 0, 0, 0)

// ---------------- ws-too-small fallback ----------------
__global__ void k_zero(float* __restrict__ out, int n) {
    int t = blockIdx.x * 256 + threadIdx.x;
    if (t < n) out[t] = 0.f;
}

// ------- weight convert fp32 -> bf16 TRANSPOSED + fragment-major K permutation ------
// Also emits projb: proj pre-scaled by DNF, bf16, fragment-major [L][128][64].
__global__ void k_wconv(const float* __restrict__ wq, const float* __restrict__ wk,
                        const float* __restrict__ wv, const float* __restrict__ wo,
                        const float* __restrict__ w1, const float* __restrict__ w2,
                        const float* __restrict__ proj,
                        unsigned short* __restrict__ wb,
                        unsigned short* __restrict__ pb) {
    int i = blockIdx.x * 256 + threadIdx.x;       // 0 .. 3,178,495
    if (i >= 3145728) {
        int j = i - 3145728;                      // 0 .. 32767
        int l = j >> 13;
        int r = j & 8191;
        int m = r >> 6, kpos = r & 63;
        int ch = kpos >> 3, hlf = (kpos >> 2) & 1, ii = kpos & 3;
        int f = ch ^ (m & 7);
        int dtrue = (f >> 2) * 32 + hlf * 16 + (f & 3) * 4 + ii;
        pb[j] = f2bf(proj[(size_t)l * 8192 + m * 64 + dtrue] * DNF);
        return;
    }
    int l = i / 786432;
    int r = i - l * 786432;
    const float* src;
    int K, N, off;
    if (r < 262144) {
        int wsel = r >> 16; int rr = r & 65535;
        src = (wsel == 0 ? wq : wsel == 1 ? wk : wsel == 2 ? wv : wo) + (size_t)l * 65536;
        K = 256; N = 256; off = rr;
    } else if (r < 524288) {
        src = w1 + (size_t)l * 262144; K = 256; N = 1024; off = r - 262144;
    } else {
        src = w2 + (size_t)l * 262144; K = 1024; N = 256; off = r - 524288;
    }
    int n = off / K, kpos = off - n * K;
    int kblk = kpos >> 6, p6 = kpos & 63;
    int ch = p6 >> 3, hlf = (p6 >> 2) & 1, ii = p6 & 3;
    int f = ch ^ (n & 7);
    int ktrue = kblk * 64 + (f >> 2) * 32 + hlf * 16 + (f & 3) * 4 + ii;
    wb[i] = f2bf(src[(size_t)ktrue * N + n]);
}

// ---------------- embed: h = emb_tok[x] + emb_pos (bf16 residual) ----------------
__global__ void k_embed(const int* __restrict__ x, const float* __restrict__ tok,
                        const float* __restrict__ pos, unsigned short* __restrict__ h) {
    int i = blockIdx.x * 256 + threadIdx.x;       // over BNQ*DD
    int d  = i & (DD - 1);
    int bn = i >> 8;
    int n  = bn & (NN - 1);
    h[i] = f2bf(tok[x[bn] * DD + d] + pos[n * DD + d]);
}

// -------- layernorm (wave per row): h bf16 -> y bf16 FRAGMENT-MAJOR; inits kmaxU --------
__global__ __launch_bounds__(256) void k_ln(const unsigned short* __restrict__ h, const float* __restrict__ s,
                                            const float* __restrict__ b, unsigned short* __restrict__ y,
                                            unsigned* __restrict__ kmaxU) {
    int t = threadIdx.x;
    if (blockIdx.x == 0 && t < 64) kmaxU[t] = 0u;
    int w = t >> 6, l = t & 63;
    int row = blockIdx.x * 4 + w;
    float4 v = ld4f(h + (size_t)row * DD + l * 4);
    float sum = v.x + v.y + v.z + v.w;
    float ss  = v.x * v.x + v.y * v.y + v.z * v.z + v.w * v.w;
#pragma unroll
    for (int m = 1; m < 64; m <<= 1) {
        sum += __shfl_xor(sum, m, 64);
        ss  += __shfl_xor(ss, m, 64);
    }
    float mean = sum * (1.f / 256.f);
    float var  = ss * (1.f / 256.f) - mean * mean;
    float inv  = rsqrtf(var + 1e-5f);
    float4 sv = *(const float4*)(s + l * 4);
    float4 bv = *(const float4*)(b + l * 4);
    float4 o;
    o.x = (v.x - mean) * inv * sv.x + bv.x;
    o.y = (v.y - mean) * inv * sv.y + bv.y;
    o.z = (v.z - mean) * inv * sv.z + bv.z;
    o.w = (v.w - mean) * inv * sv.w + bv.w;
    int c6 = (l * 4) & 63;
    int afi = c6 >> 5, hlf = (c6 >> 4) & 1, lq2 = (c6 >> 2) & 3;
    int f = afi * 4 + lq2;
    int ch = f ^ (row & 7);
    int cp = (l >> 4) * 64 + ch * 8 + hlf * 4;
    st4(y + (size_t)row * DD + cp, o);
}

// --- gelu (tanh approx): x * sigmoid(2u), exact identity; v_rcp for the division ---
__device__ __forceinline__ float gelu_tanh(float x) {
    float x2 = x * x;
    float tt = __builtin_fmaf(0.044715f * x2, x, x);
    float e  = __expf(-1.5957691216057308f * tt);   // 2*sqrt(2/pi)
    return x * __builtin_amdgcn_rcpf(1.f + e);
}

// ------ MFMA GEMM v7: 4 waves, 2x2 wave grid, 4rt x 4ct (0.5 LDS reads/MFMA), dbuf ------
template<bool RES, bool BIAS, bool GELU, bool PERMC>
__global__ __launch_bounds__(256) void k_gemm_mfma(const unsigned short* __restrict__ A,
                                                   const unsigned short* __restrict__ Wt,
                                                   const float* __restrict__ bias,
                                                   unsigned short* __restrict__ Cmat,
                                                   int K, int Nw, int ny) {
    __shared__ __align__(16) short smem[32768];   // A0|W0|A1|W1 (16KB each); reused as out-stage
    int t = threadIdx.x;
    int w = t >> 6, l = t & 63;
    int lm = l & 15, lq = l >> 4;
    int srow = l >> 3, sch = l & 7;
    int wr = w >> 1, wc = w & 1;                  // wave grid 2x2 over 8x8 fragment tiles
    int nwg = gridDim.x;
    int bid = blockIdx.x;
    int s = (bid & 7) * (nwg >> 3) + (bid >> 3);
    int brow = s / ny, bcol = s - brow * ny;
    int row0 = brow * 128, col0 = bcol * 128;

    f32x4 acc[4][4];
#pragma unroll
    for (int rr = 0; rr < 4; rr++)
#pragma unroll
        for (int cc = 0; cc < 4; cc++) acc[rr][cc] = (f32x4){0.f, 0.f, 0.f, 0.f};

    int szl = lm & 7;
    int chA0 = (lq ^ szl) << 3;
    int chA1 = ((4 + lq) ^ szl) << 3;

    auto stage = [&](short* Ad, short* Wd, int k0) {
#pragma unroll
        for (int ss = 0; ss < 4; ss++) {
            int wrow = w * 32 + ss * 8;
            GL2LDS(A + (size_t)(row0 + wrow + srow) * K + k0 + (sch << 3), Ad + wrow * 64);
            GL2LDS(Wt + (size_t)(col0 + wrow + srow) * K + k0 + (sch << 3), Wd + wrow * 64);
        }
    };

    int nit = K >> 6;
    stage(smem, smem + 8192, 0);
    __syncthreads();
    for (int it = 0; it < nit; ++it) {
        short* Ac = (it & 1) ? smem + 16384 : smem;
        short* Wc = (it & 1) ? smem + 24576 : smem + 8192;
        if (it + 1 < nit) {
            short* An = (it & 1) ? smem : smem + 16384;
            short* Wn = (it & 1) ? smem + 8192 : smem + 24576;
            stage(An, Wn, (it + 1) << 6);
        }
        bf16x8 af[4][2];
#pragma unroll
        for (int rr = 0; rr < 4; rr++) {
            const short* ar = Ac + ((wr * 4 + rr) * 16 + lm) * 64;
            af[rr][0] = *(const bf16x8*)(ar + chA0);
            af[rr][1] = *(const bf16x8*)(ar + chA1);
        }
#pragma unroll
        for (int cc = 0; cc < 4; cc++) {
            const short* br = Wc + ((wc * 4 + cc) * 16 + lm) * 64;
            bf16x8 b0 = *(const bf16x8*)(br + chA0);
            bf16x8 b1 = *(const bf16x8*)(br + chA1);
#pragma unroll
            for (int rr = 0; rr < 4; rr++) {
                acc[rr][cc] = MFMA(af[rr][0], b0, acc[rr][cc]);
                acc[rr][cc] = MFMA(af[rr][1], b1, acc[rr][cc]);
            }
        }
        __syncthreads();
    }

    if (!RES) {
        // staged coalesced bf16 epilogue (pitch 136), packed converts, optional PERMC remap
#pragma unroll
        for (int rr = 0; rr < 4; rr++) {
            int rt = wr * 4 + rr;
#pragma unroll
            for (int cc = 0; cc < 4; cc++) {
                int col = (wc * 4 + cc) * 16 + lm;
                float bi = BIAS ? bias[col0 + col] : 0.f;
                int cbase = col, fq = 0;
                if (PERMC) {
                    int c6 = col & 63;
                    int afi = c6 >> 5, hlf = (c6 >> 4) & 1, lq2 = (c6 >> 2) & 3, ii = c6 & 3;
                    fq = afi * 4 + lq2;
                    cbase = (col >> 6) * 64 + hlf * 4 + ii;
                }
#pragma unroll
                for (int r = 0; r < 4; r += 2) {
                    int R0 = rt * 16 + lq * 4 + r;
                    int R1 = R0 + 1;
                    float cv0 = acc[rr][cc][r] + bi;
                    float cv1 = acc[rr][cc][r + 1] + bi;
                    if (GELU) { cv0 = gelu_tanh(cv0); cv1 = gelu_tanh(cv1); }
                    unsigned pu = cvtpk(cv0, cv1);
                    int cp0 = PERMC ? (cbase + ((fq ^ (R0 & 7)) << 3)) : cbase;
                    int cp1 = PERMC ? (cbase + ((fq ^ (R1 & 7)) << 3)) : cbase;
                    smem[R0 * 136 + cp0] = (short)(pu & 0xffff);
                    smem[R1 * 136 + cp1] = (short)(pu >> 16);
                }
            }
        }
        __syncthreads();
        for (int e = t; e < 2048; e += 256) {
            int r = e >> 4, c16 = (e & 15) << 3;
            int4 xv = *(const int4*)(smem + r * 136 + c16);
            *(int4*)(Cmat + (size_t)(row0 + r) * Nw + col0 + c16) = xv;
        }
    } else {
        // staged coalesced bf16 residual RMW, 2 halves of 64 rows
        float* smemf = (float*)smem;          // [64][136] f32 = 34816 B
#pragma unroll
        for (int hf = 0; hf < 2; hf++) {
            __syncthreads();
            if (wr == hf) {                   // waves with wr==hf own rows [hf*64, hf*64+64)
#pragma unroll
                for (int rr = 0; rr < 4; rr++) {
                    int rloc = rr * 16 + lq * 4;
#pragma unroll
                    for (int cc = 0; cc < 4; cc++) {
                        int col = (wc * 4 + cc) * 16 + lm;
                        float bi = BIAS ? bias[col0 + col] : 0.f;
#pragma unroll
                        for (int r = 0; r < 4; r++) {
                            float cv = acc[rr][cc][r] + bi;
                            if (GELU) cv = gelu_tanh(cv);
                            smemf[(rloc + r) * 136 + col] = cv;
                        }
                    }
                }
            }
            __syncthreads();
            for (int e = t; e < 2048; e += 256) {
                int r = e >> 5, c4 = (e & 31) << 2;
                unsigned short* gp = Cmat + (size_t)(row0 + hf * 64 + r) * Nw + col0 + c4;
                ushort4 ov = *(const ushort4*)gp;
                const float* sp = smemf + r * 136 + c4;
                *(short4*)gp = pack4(bf2f(ov.x) + sp[0], bf2f(ov.y) + sp[1],
                                     bf2f(ov.z) + sp[2], bf2f(ov.w) + sp[3]);
            }
        }
    }
}

// ------ fused pre-pass (8 waves): diagq + diagk + kmax; proj pre-permuted (pb) -------
__global__ __launch_bounds__(512) void k_prep(const unsigned short* __restrict__ qg,
                                              const unsigned short* __restrict__ kg,
                                              const unsigned short* __restrict__ pb,
                                              float* __restrict__ diagq,
                                              float* __restrict__ diagk,
                                              unsigned* __restrict__ kmaxU) {
    int blk = blockIdx.x;          // bh*32 + c
    int c = blk & 31, bh = blk >> 5;
    int hh = bh & 3, b = bh >> 2;
    int n0 = c * 128;
    int t = threadIdx.x;
    int w = t >> 6, l = t & 63;
    int lm = l & 15, lq = l >> 4;
    int szl = lm & 7;
    int chA0 = (lq ^ szl) << 3;
    int chA1 = ((4 + lq) ^ szl) << 3;
    __shared__ __align__(16) short projL[8192];
    __shared__ float wmaxL[8];
    GL2LDS(pb + (size_t)t * 8, projL + w * 512);
    GL2LDS(pb + 4096 + (size_t)t * 8, projL + 4096 + w * 512);
    __syncthreads();
    int row0 = w * 16;
    size_t base = ((size_t)(b * NN) + n0 + row0 + lm) * QS + hh * DHH + (lq << 2);
    bf16x8 a0 = ldfragG(kg + base);
    bf16x8 a1 = ldfragG(kg + base + 32);
    bf16x8 q0 = ldfragG(qg + base);
    bf16x8 q1 = ldfragG(qg + base + 32);
    float sk = 0.f, sq = 0.f;
#pragma unroll
    for (int j = 0; j < 8; j++) {
        float k0 = bf2f((unsigned short)a0[j]), k1 = bf2f((unsigned short)a1[j]);
        float u0 = bf2f((unsigned short)q0[j]), u1 = bf2f((unsigned short)q1[j]);
        sk += k0 * k0 + k1 * k1;
        sq += u0 * u0 + u1 * u1;
    }
    sk += __shfl_xor(sk, 16, 64); sk += __shfl_xor(sk, 32, 64);
    sq += __shfl_xor(sq, 16, 64); sq += __shfl_xor(sq, 32, 64);
    if (lq == 0) {
        diagk[bh * NN + n0 + row0 + lm] = 0.5f * DNF * DNF * sk;
        diagq[bh * NN + n0 + row0 + lm] = 0.5f * DNF * DNF * sq;
    }
    // xpK row-max via MFMA
    f32x4 mxv = {-1e30f, -1e30f, -1e30f, -1e30f};
#pragma unroll
    for (int mt = 0; mt < 8; mt++) {
        const short* pr_ = projL + (mt * 16 + lm) * 64;
        f32x4 acc = {0.f, 0.f, 0.f, 0.f};
        acc = MFMA(a0, *(const bf16x8*)(pr_ + chA0), acc);
        acc = MFMA(a1, *(const bf16x8*)(pr_ + chA1), acc);
#pragma unroll
        for (int r = 0; r < 4; r++) mxv[r] = fmaxf(mxv[r], acc[r]);
    }
    float fm = fmaxf(fmaxf(mxv[0], mxv[1]), fmaxf(mxv[2], mxv[3]));
    fm = fmaxf(fm, __shfl_xor(fm, 1, 64));
    fm = fmaxf(fm, __shfl_xor(fm, 2, 64));
    fm = fmaxf(fm, __shfl_xor(fm, 4, 64));
    fm = fmaxf(fm, __shfl_xor(fm, 8, 64));
    fm = fmaxf(fm, __shfl_xor(fm, 16, 64));
    fm = fmaxf(fm, __shfl_xor(fm, 32, 64));
    if (l == 0) wmaxL[w] = fm;
    __syncthreads();
    if (t == 0) {
        float bm = wmaxL[0];
#pragma unroll
        for (int i = 1; i < 8; i++) bm = fmaxf(bm, wmaxL[i]);
        atomicMax(kmaxU + bh, fenc(bm));
    }
}

// ------- MFMA chunkG v2 (8 waves): G^T[d][m] = V^T Kf, z = colsum Kf; proj from pb ----
__global__ __launch_bounds__(512) void k_chunkG(const unsigned short* __restrict__ kg,
                                                const unsigned short* __restrict__ vg,
                                                const float* __restrict__ diagk,
                                                const unsigned* __restrict__ kmaxU,
                                                const unsigned short* __restrict__ pb,
                                                unsigned short* __restrict__ Gt,
                                                float* __restrict__ zs) {
    int blk = blockIdx.x;          // bh*NCC + c
    int c = blk & 31, bh = blk >> 5;
    int hh = bh & 3, b = bh >> 2;
    int t = threadIdx.x;
    int w = t >> 6, l = t & 63;
    int lm = l & 15, lq = l >> 4;
    int n0 = c * 128;
    int szl = lm & 7;
    int chA0 = (lq ^ szl) << 3;
    int chA1 = ((4 + lq) ^ szl) << 3;
    __shared__ short KfTL[128 * 132];   // Kf^T [m][j]
    __shared__ short VTL[64 * 132];     // V^T  [d][j]
    __shared__ __align__(16) short projL[8192];   // proj fragment-major
    __shared__ float dkb[128];

    GL2LDS(pb + (size_t)t * 8, projL + w * 512);
    GL2LDS(pb + 4096 + (size_t)t * 8, projL + 4096 + w * 512);
    for (int e = t; e < 2048; e += 512) {      // V transpose stage
        int j = e >> 4, d4 = (e & 15) << 2;
        ushort4 vv = *(const ushort4*)(vg + ((size_t)(b * NN) + n0 + j) * QS + hh * DHH + d4);
        VTL[(d4 + 0) * 132 + j] = (short)vv.x;
        VTL[(d4 + 1) * 132 + j] = (short)vv.y;
        VTL[(d4 + 2) * 132 + j] = (short)vv.z;
        VTL[(d4 + 3) * 132 + j] = (short)vv.w;
    }
    if (t < 128) dkb[t] = diagk[bh * NN + n0 + t];
    float km = fdec(kmaxU[bh]);
    __syncthreads();

    // xpK -> Kf^T  (wave w: j-row-tile w)
    {
        int row0 = w * 16;
        const unsigned short* abase = kg + ((size_t)(b * NN) + n0 + row0 + lm) * QS + hh * DHH + (lq << 2);
        bf16x8 a0 = ldfragG(abase);
        bf16x8 a1 = ldfragG(abase + 32);
        int j0 = row0 + lq * 4;
#pragma unroll
        for (int mt = 0; mt < 8; mt++) {
            const short* pr_ = projL + (mt * 16 + lm) * 64;
            f32x4 acc = {0.f, 0.f, 0.f, 0.f};
            acc = MFMA(a0, *(const bf16x8*)(pr_ + chA0), acc);
            acc = MFMA(a1, *(const bf16x8*)(pr_ + chA1), acc);
            short4 kv = pack4(RATIOF * (__expf(acc[0] - dkb[j0 + 0] - km) + FEPS),
                              RATIOF * (__expf(acc[1] - dkb[j0 + 1] - km) + FEPS),
                              RATIOF * (__expf(acc[2] - dkb[j0 + 2] - km) + FEPS),
                              RATIOF * (__expf(acc[3] - dkb[j0 + 3] - km) + FEPS));
            *(short4*)(KfTL + (mt * 16 + lm) * 132 + j0) = kv;
        }
    }
    __syncthreads();

    // G^T[d][m]: wave w owns d-tile w>>1, m-tiles (w&1)*4 .. +4
    {
        int dt = w >> 1, mt0 = (w & 1) * 4;
        bf16x8 va[4];
#pragma unroll
        for (int kb = 0; kb < 4; kb++)
            va[kb] = ldfragL(VTL + (dt * 16 + lm) * 132 + kb * 32 + (lq << 2));
#pragma unroll
        for (int mi = 0; mi < 4; mi++) {
            int mt = mt0 + mi;
            f32x4 acc = {0.f, 0.f, 0.f, 0.f};
#pragma unroll
            for (int kb = 0; kb < 4; kb++) {
                bf16x8 bk = ldfragL(KfTL + (mt * 16 + lm) * 132 + kb * 32 + (lq << 2));
                acc = MFMA(va[kb], bk, acc);
            }
#pragma unroll
            for (int r = 0; r < 4; r++) {
                int dd = dt * 16 + lq * 4 + r, mmo = mt * 16 + lm;
                Gt[(size_t)blk * 8192 + dd * 128 + mmo] = f2bf(acc[r]);
            }
        }
    }
    // z[m] = sum_j Kf^T[m][j]  (4 threads per m)
    {
        int m = t >> 2, qd = t & 3;
        float zz = 0.f;
        const short* kp = KfTL + m * 132 + qd * 32;
        for (int j = 0; j < 32; j++) zz += bf2f((unsigned short)kp[j]);
        zz += __shfl_xor(zz, 1, 64);
        zz += __shfl_xor(zz, 2, 64);
        if (qd == 0) zs[blk * 128 + m] = zz;
    }
}

// -------- merged exclusive scans: preload 32 values, then write prefix --------
__global__ void k_scan(unsigned short* __restrict__ G, float* __restrict__ zs) {
    int blk = blockIdx.x;
    if (blk < 2048) {
        int e = blk * 256 + threadIdx.x;   // B*H*8192 = 524288 threads
        int bh = e >> 13;
        int off = e & 8191;
        unsigned short* p = G + (long)bh * NCC * 8192 + off;
        float vals[NCC];
#pragma unroll
        for (int c = 0; c < NCC; c++) vals[c] = bf2f(p[(long)c * 8192]);
        float a = 0.f;
#pragma unroll
        for (int c = 0; c < NCC; c++) { p[(long)c * 8192] = f2bf(a); a += vals[c]; }
    } else {
        int e = (blk - 2048) * 256 + threadIdx.x;   // B*H*M = 8192 threads
        int bh = e >> 7, off = e & 127;
        float* p = zs + bh * NCC * 128 + off;
        float vals[NCC];
#pragma unroll
        for (int c = 0; c < NCC; c++) vals[c] = p[c * 128];
        float a = 0.f;
#pragma unroll
        for (int c = 0; c < NCC; c++) { p[c * 128] = a; a += vals[c]; }
    }
}

// -------- MFMA attention v5 (8 waves): one i-tile per wave; proj from pb ----
__global__ __launch_bounds__(512) void k_attn(const unsigned short* __restrict__ qg,
                                              const unsigned short* __restrict__ kg,
                                              const unsigned short* __restrict__ vg,
                                              const unsigned short* __restrict__ Gt,
                                              const float* __restrict__ zs,
                                              const float* __restrict__ diagk,
                                              const float* __restrict__ diagq,
                                              const unsigned* __restrict__ kmaxU,
                                              const unsigned short* __restrict__ pb,
                                              unsigned short* __restrict__ og) {
    int blk = blockIdx.x;
    int c = blk & 31, bh = blk >> 5;
    int hh = bh & 3, b = bh >> 2;
    int t = threadIdx.x;
    int w = t >> 6, l = t & 63;
    int lm = l & 15, lq = l >> 4;
    int n0 = c * 128;
    int szl = lm & 7;
    int chA0 = (lq ^ szl) << 3;
    int chA1 = ((4 + lq) ^ szl) << 3;

    __shared__ short KfL[128 * 132];          // Kf [j][m]; later S^T [d][m]; later out-stage
    __shared__ __align__(16) short pvt[8448]; // proj [128][64] frag-major; later V^T [64][132]
    __shared__ float zb[128], dkb[128], dqb[128];
    short* projL = pvt;
    short* VTL = pvt;
    short* STL = KfL;
    short* outL = KfL;                        // 128x68 out-staging (fits in KfL region)

    // ---- P0: stage proj (async, pre-permuted) + smalls ----
    GL2LDS(pb + (size_t)t * 8, projL + w * 512);
    GL2LDS(pb + 4096 + (size_t)t * 8, projL + 4096 + w * 512);
    if (t < 128) {
        zb[t]  = zs[blk * 128 + t];
        dkb[t] = diagk[bh * NN + n0 + t];
        dqb[t] = diagq[bh * NN + n0 + t];
    }
    float km = fdec(kmaxU[bh]);
    __syncthreads();

    // ---- P1': xqT[m][i] = proj @ Q^T for wave's i-tile w; Qf -> registers ----
    bf16x8 qfrag[4];
    float dpart;
    {
        int it = w;
        const unsigned short* qbase = qg + ((size_t)(b * NN) + n0 + it * 16 + lm) * QS + hh * DHH + (lq << 2);
        bf16x8 qb0 = ldfragG(qbase);
        bf16x8 qb1 = ldfragG(qbase + 32);
        f32x4 xq[8];
#pragma unroll
        for (int mt = 0; mt < 8; mt++) {
            const short* pr_ = projL + (mt * 16 + lm) * 64;
            f32x4 acc = {0.f, 0.f, 0.f, 0.f};
            acc = MFMA(*(const bf16x8*)(pr_ + chA0), qb0, acc);
            acc = MFMA(*(const bf16x8*)(pr_ + chA1), qb1, acc);
            xq[mt] = acc;
        }
        float mv = -1e30f;
#pragma unroll
        for (int mt = 0; mt < 8; mt++)
#pragma unroll
            for (int r = 0; r < 4; r++) mv = fmaxf(mv, xq[mt][r]);
        mv = fmaxf(mv, __shfl_xor(mv, 16, 64));
        mv = fmaxf(mv, __shfl_xor(mv, 32, 64));
        float dq = dqb[it * 16 + lm];
        float dz = 0.f;
#pragma unroll
        for (int mt = 0; mt < 8; mt++)
#pragma unroll
            for (int r = 0; r < 4; r++) {
                float e_ = RATIOF * (__expf(xq[mt][r] - dq - mv) + FEPS);
                xq[mt][r] = e_;
                dz += e_ * zb[mt * 16 + lq * 4 + r];
            }
        dpart = dz;
#pragma unroll
        for (int p = 0; p < 4; p++) qfrag[p] = pack8(xq[2 * p], xq[2 * p + 1]);
    }

    // ---- P2: Kf -> KfL[j][m] (wave's j-tile w) ----
    {
        int row0 = w * 16;
        const unsigned short* abase = kg + ((size_t)(b * NN) + n0 + row0 + lm) * QS + hh * DHH + (lq << 2);
        bf16x8 a0 = ldfragG(abase);
        bf16x8 a1 = ldfragG(abase + 32);
        int rg = row0 + lq * 4;
#pragma unroll
        for (int mt = 0; mt < 8; mt++) {
            const short* pr_ = projL + (mt * 16 + lm) * 64;
            f32x4 acc = {0.f, 0.f, 0.f, 0.f};
            acc = MFMA(a0, *(const bf16x8*)(pr_ + chA0), acc);
            acc = MFMA(a1, *(const bf16x8*)(pr_ + chA1), acc);
#pragma unroll
            for (int r = 0; r < 4; r++) {
                float e_ = RATIOF * (__expf(acc[r] - dkb[rg + r] - km) + FEPS);
                KfL[(rg + r) * 132 + mt * 16 + lm] = (short)f2bf(e_);
            }
        }
    }
    __syncthreads();   // barrier A: KfL complete; projL reads done

    // ---- V^T stage into projL region ----
    for (int e = t; e < 2048; e += 512) {
        int j = e >> 4, d4 = (e & 15) << 2;
        ushort4 vv = *(const ushort4*)(vg + ((size_t)(b * NN) + n0 + j) * QS + hh * DHH + d4);
        VTL[(d4 + 0) * 132 + j] = (short)vv.x;
        VTL[(d4 + 1) * 132 + j] = (short)vv.y;
        VTL[(d4 + 2) * 132 + j] = (short)vv.z;
        VTL[(d4 + 3) * 132 + j] = (short)vv.w;
    }

    // ---- P3': attnT[j][i] = Kf @ Qf^T (causal j<=i=w); B-frags in registers ----
    bf16x8 pfrag[4];
    float dena = 0.f;
    __builtin_amdgcn_s_setprio(1);
    {
        int it = w;
#pragma unroll
        for (int p = 0; p < 4; p++) {
            f32x4 a0 = {0.f, 0.f, 0.f, 0.f};
            f32x4 a1 = {0.f, 0.f, 0.f, 0.f};
            int jt0 = 2 * p, jt1 = 2 * p + 1;
            if (jt0 <= it) {
#pragma unroll
                for (int kb = 0; kb < 4; kb++)
                    a0 = MFMA(ldfragL(KfL + (jt0 * 16 + lm) * 132 + kb * 32 + (lq << 2)), qfrag[kb], a0);
                if (jt0 == it) {
#pragma unroll
                    for (int r = 0; r < 4; r++) if (lq * 4 + r > lm) a0[r] = 0.f;
                }
                dena += a0[0] + a0[1] + a0[2] + a0[3];
            }
            if (jt1 <= it) {
#pragma unroll
                for (int kb = 0; kb < 4; kb++)
                    a1 = MFMA(ldfragL(KfL + (jt1 * 16 + lm) * 132 + kb * 32 + (lq << 2)), qfrag[kb], a1);
                if (jt1 == it) {
#pragma unroll
                    for (int r = 0; r < 4; r++) if (lq * 4 + r > lm) a1[r] = 0.f;
                }
                dena += a1[0] + a1[1] + a1[2] + a1[3];
            }
            pfrag[p] = pack8(a0, a1);
        }
    }
    __builtin_amdgcn_s_setprio(0);
    float den = dena + dpart;
    den += __shfl_xor(den, 16, 64);
    den += __shfl_xor(den, 32, 64);
    float rden = __builtin_amdgcn_rcpf(den);
    __syncthreads();   // barrier B: KfL reads done

    // ---- S^T stage into KfL region ----
    {
        const unsigned short* gp = Gt + (size_t)blk * 8192;
        for (int e4 = t; e4 < 2048; e4 += 512) {
            int d = e4 >> 5, m4 = (e4 & 31) << 2;
            ushort4 gv = *(const ushort4*)(gp + d * 128 + m4);
            short4 sv = {(short)gv.x, (short)gv.y, (short)gv.z, (short)gv.w};
            *(short4*)(STL + d * 132 + m4) = sv;
        }
    }
    __syncthreads();   // barrier C

    // ---- P4': out^T[d][i] = V^T @ attnT + S^T @ Qf^T ----
    short4 ovr[4];
    __builtin_amdgcn_s_setprio(1);
    {
        int it = w;
        int kbmax = it >> 1;
#pragma unroll
        for (int dt = 0; dt < 4; dt++) {
            f32x4 acc = {0.f, 0.f, 0.f, 0.f};
#pragma unroll
            for (int kb = 0; kb < 4; kb++) {
                if (kb <= kbmax)
                    acc = MFMA(ldfragL(VTL + (dt * 16 + lm) * 132 + kb * 32 + (lq << 2)), pfrag[kb], acc);
            }
#pragma unroll
            for (int kb = 0; kb < 4; kb++)
                acc = MFMA(ldfragL(STL + (dt * 16 + lm) * 132 + kb * 32 + (lq << 2)), qfrag[kb], acc);
            ovr[dt] = pack4(acc[0] * rden, acc[1] * rden, acc[2] * rden, acc[3] * rden);
        }
    }
    __builtin_amdgcn_s_setprio(0);
    __syncthreads();   // barrier D: all VTL/STL reads done; reuse KfL as out-stage

    // ---- transpose-stage to LDS [i][d] (pitch 68), then PERMUTED coalesced global write ----
#pragma unroll
    for (int dt = 0; dt < 4; dt++)
        *(short4*)(outL + (w * 16 + lm) * 68 + dt * 16 + lq * 4) = ovr[dt];
    __syncthreads();   // barrier E
    for (int e = t; e < 2048; e += 512) {
        int r = e >> 4, c4 = (e & 15) << 2;       // true col group
        int afi = c4 >> 5, hlf = (c4 >> 4) & 1, lq2 = (c4 >> 2) & 3;
        int f = afi * 4 + lq2;
        int cp = ((f ^ (r & 7)) << 3) + hlf * 4;
        ushort4 xv = *(const ushort4*)(outL + r * 68 + c4);
        *(ushort4*)(og + ((size_t)(b * NN) + n0 + r) * DD + hh * 64 + cp) = xv;
    }
}

// ---------------- classifier (h bf16) ----------------
__global__ void k_cls(const unsigned short* __restrict__ h, const float* __restrict__ wc,
                      const float* __restrict__ bc, float* __restrict__ out) {
    int t = threadIdx.x;
    if (t >= BB * COUT) return;
    int b = t / COUT, c = t % COUT;
    float a = bc[c];
    for (int d = 0; d < DD; d++) a += bf2f(h[(size_t)b * NN * DD + d]) * wc[d * COUT + c];
    out[t] = a;
}

extern "C" void kernel_launch(void* const* d_in, const int* in_sizes, int n_in,
                              void* d_out, int out_size, void* d_ws, size_t ws_size,
                              hipStream_t stream) {
    const int*   x    = (const int*)d_in[0];
    const float* tok  = (const float*)d_in[1];
    const float* pos  = (const float*)d_in[2];
    const float* proj = (const float*)d_in[3];
    const float* ln1s = (const float*)d_in[4];
    const float* ln1b = (const float*)d_in[5];
    const float* wq   = (const float*)d_in[6];
    const float* wk   = (const float*)d_in[7];
    const float* wv   = (const float*)d_in[8];
    const float* wo   = (const float*)d_in[9];
    const float* bo   = (const float*)d_in[10];
    const float* ln2s = (const float*)d_in[11];
    const float* ln2b = (const float*)d_in[12];
    const float* w1   = (const float*)d_in[13];
    const float* b1   = (const float*)d_in[14];
    const float* w2   = (const float*)d_in[15];
    const float* b2   = (const float*)d_in[16];
    const float* wcls = (const float*)d_in[17];
    const float* bcls = (const float*)d_in[18];
    float* out = (float*)d_out;
    float* ws  = (float*)d_ws;

    // ---- layout (float units; SZ = 16,777,216); h bf16 ----
    const long SZ = (long)BNQ * DD;
    unsigned short* h = (unsigned short*)ws;                     // bf16 residual (SZ elems)
    unsigned short* yo = (unsigned short*)(ws + SZ);             // y / o (SZ bf16)
    unsigned short* qkv = (unsigned short*)(ws + 3 * SZ / 2);    // [65536][768] bf16
    unsigned short* G  = (unsigned short*)(ws + 3 * SZ);         // SZ bf16 (G^T per chunk)
    unsigned short* tbuf = qkv;                                  // overlays qkv+G (4SZ bf16)
    float* diagk  = ws + 7 * SZ / 2;                             // 262144
    float* diagq  = diagk + 262144;                              // 262144
    float* rowmax = diagq + 262144;                              // 262144 (unused, layout keep)
    float* kmax   = rowmax + 262144;                             // 64 (pad 256)
    float* zs     = kmax + 256;                                  // 262144
    unsigned short* wb = (unsigned short*)(zs + 262144);         // 3,145,728 bf16
    unsigned short* projb = wb + 3145728;                        // 32,768 bf16 (frag-major proj)
    unsigned* kmaxU = (unsigned*)kmax;

    size_t needed = (size_t)(7 * SZ / 2 + 4 * 262144 + 256) * 4 + (size_t)(3145728 + 32768) * 2;
    if (ws_size < needed) {
        k_zero<<<1, 256, 0, stream>>>(out, out_size);
        return;
    }

    unsigned short* q = qkv;            // stride QS views
    unsigned short* k = qkv + 256;
    unsigned short* v = qkv + 512;

    k_wconv<<<12416, 256, 0, stream>>>(wq, wk, wv, wo, w1, w2, proj, wb, projb);
    k_embed<<<BNQ, 256, 0, stream>>>(x, tok, pos, h);

    const size_t LW = 786432;   // per-layer stride in wb

    for (int l = 0; l < LL; l++) {
        const unsigned short* pbL = projb + (size_t)l * 8192;
        const unsigned short* wqkvT = wb + (size_t)l * LW;       // [768][256] concat q|k|v
        const unsigned short* woT = wqkvT + 3 * 65536;
        const unsigned short* w1T = woT + 65536;
        const unsigned short* w2T = w1T + 262144;
        k_ln<<<BNQ / 4, 256, 0, stream>>>(h, ln1s + l * DD, ln1b + l * DD, yo, kmaxU);
        k_gemm_mfma<false, false, false, false><<<512 * 6, 256, 0, stream>>>(yo, wqkvT, nullptr, qkv, DD, QS, 6);
        k_prep<<<BB * HH * NCC, 512, 0, stream>>>(q, k, pbL, diagq, diagk, kmaxU);
        k_chunkG<<<BB * HH * NCC, 512, 0, stream>>>(k, v, diagk, kmaxU, pbL, G, zs);
        k_scan<<<2080, 256, 0, stream>>>(G, zs);
        k_attn<<<BB * HH * NCC, 512, 0, stream>>>(q, k, v, G, zs, diagk, diagq, kmaxU, pbL, yo);
        k_gemm_mfma<true, true, false, false><<<512 * 2, 256, 0, stream>>>(yo, woT, bo + l * DD, h, DD, DD, 2);
        k_ln<<<BNQ / 4, 256, 0, stream>>>(h, ln2s + l * DD, ln2b + l * DD, yo, kmaxU);
        k_gemm_mfma<false, true, true, true><<<512 * 8, 256, 0, stream>>>(yo, w1T, b1 + l * 1024, tbuf, DD, 1024, 8);
        k_gemm_mfma<true, true, false, false><<<512 * 2, 256, 0, stream>>>(tbuf, w2T, b2 + l * DD, h, 1024, DD, 2);
    }
    k_cls<<<1, 256, 0, stream>>>(h, wcls, bcls, out);
}

// Round 25
// 1401.711 us; speedup vs baseline: 1.0504x; 1.0504x over previous
//
#include <hip/hip_runtime.h>
#include <hip/hip_bf16.h>

#define BB   16
#define NN   4096
#define DD   256
#define QS   768                    // fused qkv row stride
#define HH   4
#define DHH  64
#define MM   128
#define LL   4
#define NCC  32
#define COUT 10
#define BNQ  (BB*NN)                // 65536 rows
#define DNF  0.35355339059327373f   // 64^-0.25
#define RATIOF 0.08838834764831845f // 128^-0.5
#define FEPS 1e-4f

typedef __attribute__((ext_vector_type(8))) short bf16x8;
typedef __attribute__((ext_vector_type(4))) float f32x4;

// ---- bf16 helpers (raw ushort representation) ----
__device__ __forceinline__ float bf2f(unsigned short u) {
    return __uint_as_float(((unsigned)u) << 16);
}
__device__ __forceinline__ unsigned short f2bf(float x) {
    unsigned u = __float_as_uint(x);
    u += 0x7FFF + ((u >> 16) & 1);   // round-nearest-even
    return (unsigned short)(u >> 16);
}
// hardware packed f32x2 -> bf16x2 (RNE)
__device__ __forceinline__ unsigned cvtpk(float lo, float hi) {
    unsigned r;
    asm("v_cvt_pk_bf16_f32 %0, %1, %2" : "=v"(r) : "v"(lo), "v"(hi));
    return r;
}
__device__ __forceinline__ short4 pack4(float a, float b, float c, float d) {
    union { unsigned u[2]; short4 s; } x;
    x.u[0] = cvtpk(a, b);
    x.u[1] = cvtpk(c, d);
    return x.s;
}
__device__ __forceinline__ float4 ld4f(const float* p) { return *(const float4*)p; }
__device__ __forceinline__ float4 ld4f(const unsigned short* p) {
    ushort4 u = *(const ushort4*)p;
    return make_float4(bf2f(u.x), bf2f(u.y), bf2f(u.z), bf2f(u.w));
}
__device__ __forceinline__ void st4(float* p, float4 v) { *(float4*)p = v; }
__device__ __forceinline__ void st4(unsigned short* p, float4 v) {
    *(short4*)p = pack4(v.x, v.y, v.z, v.w);
}

// ---- monotone float<->uint encoding for atomicMax on floats ----
__device__ __forceinline__ unsigned fenc(float f) {
    unsigned u = __float_as_uint(f);
    return (u >> 31) ? ~u : (u | 0x80000000u);
}
__device__ __forceinline__ float fdec(unsigned e) {
    return __uint_as_float((e >> 31) ? (e ^ 0x80000000u) : ~e);
}

// ---- async global->LDS 16B copy (linear dest: wave-uniform base + lane*16) ----
#define GL2LDS(g, p) __builtin_amdgcn_global_load_lds( \
    (const __attribute__((address_space(1))) void*)(g), \
    (__attribute__((address_space(3))) void*)(p), 16, 0, 0)

// ---- MFMA fragment loaders ----
__device__ __forceinline__ bf16x8 ldfragL(const short* p) {
    short4 lo = *(const short4*)p;
    short4 hi = *(const short4*)(p + 16);
    bf16x8 f = {lo.x, lo.y, lo.z, lo.w, hi.x, hi.y, hi.z, hi.w};
    return f;
}
__device__ __forceinline__ bf16x8 ldfragG(const unsigned short* p) {
    ushort4 lo = *(const ushort4*)p;
    ushort4 hi = *(const ushort4*)(p + 16);
    bf16x8 f = {(short)lo.x, (short)lo.y, (short)lo.z, (short)lo.w,
                (short)hi.x, (short)hi.y, (short)hi.z, (short)hi.w};
    return f;
}
// C-tile pair -> B-fragment via packed converts
__device__ __forceinline__ bf16x8 pack8(f32x4 lo, f32x4 hi) {
    union { unsigned u[4]; bf16x8 v; } x;
    x.u[0] = cvtpk(lo[0], lo[1]);
    x.u[1] = cvtpk(lo[2], lo[3]);
    x.u[2] = cvtpk(hi[0], hi[1]);
    x.u[3] = cvtpk(hi[2], hi[3]);
    return x.v;
}
#define MFMA(a, b, c) __builtin_amdgcn_mfma_f32_16x16x32_bf16((a), (b), (c), 0, 0, 0)

// ---------------- ws-too-small fallback ----------------
__global__ void k_zero(float* __restrict__ out, int n) {
    int t = blockIdx.x * 256 + threadIdx.x;
    if (t < n) out[t] = 0.f;
}

// ------- weight convert fp32 -> bf16 TRANSPOSED + fragment-major K permutation ------
// Also emits projb: proj pre-scaled by DNF, bf16, fragment-major [L][128][64].
__global__ void k_wconv(const float* __restrict__ wq, const float* __restrict__ wk,
                        const float* __restrict__ wv, const float* __restrict__ wo,
                        const float* __restrict__ w1, const float* __restrict__ w2,
                        const float* __restrict__ proj,
                        unsigned short* __restrict__ wb,
                        unsigned short* __restrict__ pb) {
    int i = blockIdx.x * 256 + threadIdx.x;       // 0 .. 3,178,495
    if (i >= 3145728) {
        int j = i - 3145728;                      // 0 .. 32767
        int l = j >> 13;
        int r = j & 8191;
        int m = r >> 6, kpos = r & 63;
        int ch = kpos >> 3, hlf = (kpos >> 2) & 1, ii = kpos & 3;
        int f = ch ^ (m & 7);
        int dtrue = (f >> 2) * 32 + hlf * 16 + (f & 3) * 4 + ii;
        pb[j] = f2bf(proj[(size_t)l * 8192 + m * 64 + dtrue] * DNF);
        return;
    }
    int l = i / 786432;
    int r = i - l * 786432;
    const float* src;
    int K, N, off;
    if (r < 262144) {
        int wsel = r >> 16; int rr = r & 65535;
        src = (wsel == 0 ? wq : wsel == 1 ? wk : wsel == 2 ? wv : wo) + (size_t)l * 65536;
        K = 256; N = 256; off = rr;
    } else if (r < 524288) {
        src = w1 + (size_t)l * 262144; K = 256; N = 1024; off = r - 262144;
    } else {
        src = w2 + (size_t)l * 262144; K = 1024; N = 256; off = r - 524288;
    }
    int n = off / K, kpos = off - n * K;
    int kblk = kpos >> 6, p6 = kpos & 63;
    int ch = p6 >> 3, hlf = (p6 >> 2) & 1, ii = p6 & 3;
    int f = ch ^ (n & 7);
    int ktrue = kblk * 64 + (f >> 2) * 32 + hlf * 16 + (f & 3) * 4 + ii;
    wb[i] = f2bf(src[(size_t)ktrue * N + n]);
}

// ---------------- embed: h = emb_tok[x] + emb_pos (bf16 residual) ----------------
__global__ void k_embed(const int* __restrict__ x, const float* __restrict__ tok,
                        const float* __restrict__ pos, unsigned short* __restrict__ h) {
    int i = blockIdx.x * 256 + threadIdx.x;       // over BNQ*DD
    int d  = i & (DD - 1);
    int bn = i >> 8;
    int n  = bn & (NN - 1);
    h[i] = f2bf(tok[x[bn] * DD + d] + pos[n * DD + d]);
}

// -------- layernorm (wave per row): h bf16 -> y bf16 FRAGMENT-MAJOR; inits kmaxU --------
__global__ __launch_bounds__(256) void k_ln(const unsigned short* __restrict__ h, const float* __restrict__ s,
                                            const float* __restrict__ b, unsigned short* __restrict__ y,
                                            unsigned* __restrict__ kmaxU) {
    int t = threadIdx.x;
    if (blockIdx.x == 0 && t < 64) kmaxU[t] = 0u;
    int w = t >> 6, l = t & 63;
    int row = blockIdx.x * 4 + w;
    float4 v = ld4f(h + (size_t)row * DD + l * 4);
    float sum = v.x + v.y + v.z + v.w;
    float ss  = v.x * v.x + v.y * v.y + v.z * v.z + v.w * v.w;
#pragma unroll
    for (int m = 1; m < 64; m <<= 1) {
        sum += __shfl_xor(sum, m, 64);
        ss  += __shfl_xor(ss, m, 64);
    }
    float mean = sum * (1.f / 256.f);
    float var  = ss * (1.f / 256.f) - mean * mean;
    float inv  = rsqrtf(var + 1e-5f);
    float4 sv = *(const float4*)(s + l * 4);
    float4 bv = *(const float4*)(b + l * 4);
    float4 o;
    o.x = (v.x - mean) * inv * sv.x + bv.x;
    o.y = (v.y - mean) * inv * sv.y + bv.y;
    o.z = (v.z - mean) * inv * sv.z + bv.z;
    o.w = (v.w - mean) * inv * sv.w + bv.w;
    int c6 = (l * 4) & 63;
    int afi = c6 >> 5, hlf = (c6 >> 4) & 1, lq2 = (c6 >> 2) & 3;
    int f = afi * 4 + lq2;
    int ch = f ^ (row & 7);
    int cp = (l >> 4) * 64 + ch * 8 + hlf * 4;
    st4(y + (size_t)row * DD + cp, o);
}

// --- gelu (tanh approx): x * sigmoid(2u), exact identity; v_rcp for the division ---
__device__ __forceinline__ float gelu_tanh(float x) {
    float x2 = x * x;
    float tt = __builtin_fmaf(0.044715f * x2, x, x);
    float e  = __expf(-1.5957691216057308f * tt);   // 2*sqrt(2/pi)
    return x * __builtin_amdgcn_rcpf(1.f + e);
}

// ------ MFMA GEMM v6: 8 waves, 2rt x 4ct wave tile (LDS reads 18->12/iter), dbuf ------
template<bool RES, bool BIAS, bool GELU, bool PERMC>
__global__ __launch_bounds__(512) void k_gemm_mfma(const unsigned short* __restrict__ A,
                                                   const unsigned short* __restrict__ Wt,
                                                   const float* __restrict__ bias,
                                                   unsigned short* __restrict__ Cmat,
                                                   int K, int Nw, int ny) {
    __shared__ __align__(16) short smem[32768];   // A0|W0|A1|W1 (16KB each); reused as out-stage
    int t = threadIdx.x;
    int w = t >> 6, l = t & 63;
    int lm = l & 15, lq = l >> 4;
    int srow = l >> 3, sch = l & 7;
    int wr = w >> 1, wc = w & 1;                  // wave grid 4x2 over 8x8 fragment tiles
    int nwg = gridDim.x;
    int bid = blockIdx.x;
    int s = (bid & 7) * (nwg >> 3) + (bid >> 3);
    int brow = s / ny, bcol = s - brow * ny;
    int row0 = brow * 128, col0 = bcol * 128;

    f32x4 acc[2][4];
#pragma unroll
    for (int rr = 0; rr < 2; rr++)
#pragma unroll
        for (int cc = 0; cc < 4; cc++) acc[rr][cc] = (f32x4){0.f, 0.f, 0.f, 0.f};

    int szl = lm & 7;
    int chA0 = (lq ^ szl) << 3;
    int chA1 = ((4 + lq) ^ szl) << 3;

    auto stage = [&](short* Ad, short* Wd, int k0) {
#pragma unroll
        for (int ss = 0; ss < 2; ss++) {
            int wrow = w * 16 + ss * 8;
            GL2LDS(A + (size_t)(row0 + wrow + srow) * K + k0 + (sch << 3), Ad + wrow * 64);
            GL2LDS(Wt + (size_t)(col0 + wrow + srow) * K + k0 + (sch << 3), Wd + wrow * 64);
        }
    };

    int nit = K >> 6;
    stage(smem, smem + 8192, 0);
    __syncthreads();
    for (int it = 0; it < nit; ++it) {
        short* Ac = (it & 1) ? smem + 16384 : smem;
        short* Wc = (it & 1) ? smem + 24576 : smem + 8192;
        if (it + 1 < nit) {
            short* An = (it & 1) ? smem : smem + 16384;
            short* Wn = (it & 1) ? smem + 8192 : smem + 24576;
            stage(An, Wn, (it + 1) << 6);
        }
        bf16x8 af[2][2];
#pragma unroll
        for (int rr = 0; rr < 2; rr++) {
            const short* ar = Ac + ((wr * 2 + rr) * 16 + lm) * 64;
            af[rr][0] = *(const bf16x8*)(ar + chA0);
            af[rr][1] = *(const bf16x8*)(ar + chA1);
        }
#pragma unroll
        for (int cc = 0; cc < 4; cc++) {
            const short* br = Wc + ((wc * 4 + cc) * 16 + lm) * 64;
            bf16x8 b0 = *(const bf16x8*)(br + chA0);
            bf16x8 b1 = *(const bf16x8*)(br + chA1);
#pragma unroll
            for (int rr = 0; rr < 2; rr++) {
                acc[rr][cc] = MFMA(af[rr][0], b0, acc[rr][cc]);
                acc[rr][cc] = MFMA(af[rr][1], b1, acc[rr][cc]);
            }
        }
        __syncthreads();
    }

    if (!RES) {
        // staged coalesced bf16 epilogue (pitch 136), packed converts, optional PERMC remap
#pragma unroll
        for (int rr = 0; rr < 2; rr++) {
            int rt = wr * 2 + rr;
#pragma unroll
            for (int cc = 0; cc < 4; cc++) {
                int col = (wc * 4 + cc) * 16 + lm;
                float bi = BIAS ? bias[col0 + col] : 0.f;
                int cbase = col, fq = 0;
                if (PERMC) {
                    int c6 = col & 63;
                    int afi = c6 >> 5, hlf = (c6 >> 4) & 1, lq2 = (c6 >> 2) & 3, ii = c6 & 3;
                    fq = afi * 4 + lq2;
                    cbase = (col >> 6) * 64 + hlf * 4 + ii;
                }
#pragma unroll
                for (int r = 0; r < 4; r += 2) {
                    int R0 = rt * 16 + lq * 4 + r;
                    int R1 = R0 + 1;
                    float cv0 = acc[rr][cc][r] + bi;
                    float cv1 = acc[rr][cc][r + 1] + bi;
                    if (GELU) { cv0 = gelu_tanh(cv0); cv1 = gelu_tanh(cv1); }
                    unsigned pu = cvtpk(cv0, cv1);
                    int cp0 = PERMC ? (cbase + ((fq ^ (R0 & 7)) << 3)) : cbase;
                    int cp1 = PERMC ? (cbase + ((fq ^ (R1 & 7)) << 3)) : cbase;
                    smem[R0 * 136 + cp0] = (short)(pu & 0xffff);
                    smem[R1 * 136 + cp1] = (short)(pu >> 16);
                }
            }
        }
        __syncthreads();
        for (int e = t; e < 2048; e += 512) {
            int r = e >> 4, c16 = (e & 15) << 3;
            int4 xv = *(const int4*)(smem + r * 136 + c16);
            *(int4*)(Cmat + (size_t)(row0 + r) * Nw + col0 + c16) = xv;
        }
    } else {
        // staged coalesced bf16 residual RMW, 2 halves of 64 rows
        float* smemf = (float*)smem;          // [64][136] f32 = 34816 B
#pragma unroll
        for (int hf = 0; hf < 2; hf++) {
            __syncthreads();
            if ((w >> 2) == hf) {             // wr in {2hf, 2hf+1}
#pragma unroll
                for (int rr = 0; rr < 2; rr++) {
                    int rloc = ((wr & 1) * 2 + rr) * 16 + lq * 4;
#pragma unroll
                    for (int cc = 0; cc < 4; cc++) {
                        int col = (wc * 4 + cc) * 16 + lm;
                        float bi = BIAS ? bias[col0 + col] : 0.f;
#pragma unroll
                        for (int r = 0; r < 4; r++) {
                            float cv = acc[rr][cc][r] + bi;
                            if (GELU) cv = gelu_tanh(cv);
                            smemf[(rloc + r) * 136 + col] = cv;
                        }
                    }
                }
            }
            __syncthreads();
            for (int e = t; e < 2048; e += 512) {
                int r = e >> 5, c4 = (e & 31) << 2;
                unsigned short* gp = Cmat + (size_t)(row0 + hf * 64 + r) * Nw + col0 + c4;
                ushort4 ov = *(const ushort4*)gp;
                const float* sp = smemf + r * 136 + c4;
                *(short4*)gp = pack4(bf2f(ov.x) + sp[0], bf2f(ov.y) + sp[1],
                                     bf2f(ov.z) + sp[2], bf2f(ov.w) + sp[3]);
            }
        }
    }
}

// ------ fused pre-pass (8 waves): diagk + kmax only (diagq moved into k_attn) -------
__global__ __launch_bounds__(512) void k_prep(const unsigned short* __restrict__ kg,
                                              const unsigned short* __restrict__ pb,
                                              float* __restrict__ diagk,
                                              unsigned* __restrict__ kmaxU) {
    int blk = blockIdx.x;          // bh*32 + c
    int c = blk & 31, bh = blk >> 5;
    int hh = bh & 3, b = bh >> 2;
    int n0 = c * 128;
    int t = threadIdx.x;
    int w = t >> 6, l = t & 63;
    int lm = l & 15, lq = l >> 4;
    int szl = lm & 7;
    int chA0 = (lq ^ szl) << 3;
    int chA1 = ((4 + lq) ^ szl) << 3;
    __shared__ __align__(16) short projL[8192];
    __shared__ float wmaxL[8];
    GL2LDS(pb + (size_t)t * 8, projL + w * 512);
    GL2LDS(pb + 4096 + (size_t)t * 8, projL + 4096 + w * 512);
    __syncthreads();
    int row0 = w * 16;
    size_t base = ((size_t)(b * NN) + n0 + row0 + lm) * QS + hh * DHH + (lq << 2);
    bf16x8 a0 = ldfragG(kg + base);
    bf16x8 a1 = ldfragG(kg + base + 32);
    float sk = 0.f;
#pragma unroll
    for (int j = 0; j < 8; j++) {
        float k0 = bf2f((unsigned short)a0[j]), k1 = bf2f((unsigned short)a1[j]);
        sk += k0 * k0 + k1 * k1;
    }
    sk += __shfl_xor(sk, 16, 64); sk += __shfl_xor(sk, 32, 64);
    if (lq == 0) {
        diagk[bh * NN + n0 + row0 + lm] = 0.5f * DNF * DNF * sk;
    }
    // xpK row-max via MFMA
    f32x4 mxv = {-1e30f, -1e30f, -1e30f, -1e30f};
#pragma unroll
    for (int mt = 0; mt < 8; mt++) {
        const short* pr_ = projL + (mt * 16 + lm) * 64;
        f32x4 acc = {0.f, 0.f, 0.f, 0.f};
        acc = MFMA(a0, *(const bf16x8*)(pr_ + chA0), acc);
        acc = MFMA(a1, *(const bf16x8*)(pr_ + chA1), acc);
#pragma unroll
        for (int r = 0; r < 4; r++) mxv[r] = fmaxf(mxv[r], acc[r]);
    }
    float fm = fmaxf(fmaxf(mxv[0], mxv[1]), fmaxf(mxv[2], mxv[3]));
    fm = fmaxf(fm, __shfl_xor(fm, 1, 64));
    fm = fmaxf(fm, __shfl_xor(fm, 2, 64));
    fm = fmaxf(fm, __shfl_xor(fm, 4, 64));
    fm = fmaxf(fm, __shfl_xor(fm, 8, 64));
    fm = fmaxf(fm, __shfl_xor(fm, 16, 64));
    fm = fmaxf(fm, __shfl_xor(fm, 32, 64));
    if (l == 0) wmaxL[w] = fm;
    __syncthreads();
    if (t == 0) {
        float bm = wmaxL[0];
#pragma unroll
        for (int i = 1; i < 8; i++) bm = fmaxf(bm, wmaxL[i]);
        atomicMax(kmaxU + bh, fenc(bm));
    }
}

// ------- MFMA chunkG v2 (8 waves): G^T[d][m] = V^T Kf, z = colsum Kf; proj from pb ----
__global__ __launch_bounds__(512) void k_chunkG(const unsigned short* __restrict__ kg,
                                                const unsigned short* __restrict__ vg,
                                                const float* __restrict__ diagk,
                                                const unsigned* __restrict__ kmaxU,
                                                const unsigned short* __restrict__ pb,
                                                unsigned short* __restrict__ Gt,
                                                float* __restrict__ zs) {
    int blk = blockIdx.x;          // bh*NCC + c
    int c = blk & 31, bh = blk >> 5;
    int hh = bh & 3, b = bh >> 2;
    int t = threadIdx.x;
    int w = t >> 6, l = t & 63;
    int lm = l & 15, lq = l >> 4;
    int n0 = c * 128;
    int szl = lm & 7;
    int chA0 = (lq ^ szl) << 3;
    int chA1 = ((4 + lq) ^ szl) << 3;
    __shared__ short KfTL[128 * 132];   // Kf^T [m][j]
    __shared__ short VTL[64 * 132];     // V^T  [d][j]
    __shared__ __align__(16) short projL[8192];   // proj fragment-major
    __shared__ float dkb[128];

    GL2LDS(pb + (size_t)t * 8, projL + w * 512);
    GL2LDS(pb + 4096 + (size_t)t * 8, projL + 4096 + w * 512);
    for (int e = t; e < 2048; e += 512) {      // V transpose stage
        int j = e >> 4, d4 = (e & 15) << 2;
        ushort4 vv = *(const ushort4*)(vg + ((size_t)(b * NN) + n0 + j) * QS + hh * DHH + d4);
        VTL[(d4 + 0) * 132 + j] = (short)vv.x;
        VTL[(d4 + 1) * 132 + j] = (short)vv.y;
        VTL[(d4 + 2) * 132 + j] = (short)vv.z;
        VTL[(d4 + 3) * 132 + j] = (short)vv.w;
    }
    if (t < 128) dkb[t] = diagk[bh * NN + n0 + t];
    float km = fdec(kmaxU[bh]);
    __syncthreads();

    // xpK -> Kf^T  (wave w: j-row-tile w)
    {
        int row0 = w * 16;
        const unsigned short* abase = kg + ((size_t)(b * NN) + n0 + row0 + lm) * QS + hh * DHH + (lq << 2);
        bf16x8 a0 = ldfragG(abase);
        bf16x8 a1 = ldfragG(abase + 32);
        int j0 = row0 + lq * 4;
#pragma unroll
        for (int mt = 0; mt < 8; mt++) {
            const short* pr_ = projL + (mt * 16 + lm) * 64;
            f32x4 acc = {0.f, 0.f, 0.f, 0.f};
            acc = MFMA(a0, *(const bf16x8*)(pr_ + chA0), acc);
            acc = MFMA(a1, *(const bf16x8*)(pr_ + chA1), acc);
            short4 kv = pack4(RATIOF * (__expf(acc[0] - dkb[j0 + 0] - km) + FEPS),
                              RATIOF * (__expf(acc[1] - dkb[j0 + 1] - km) + FEPS),
                              RATIOF * (__expf(acc[2] - dkb[j0 + 2] - km) + FEPS),
                              RATIOF * (__expf(acc[3] - dkb[j0 + 3] - km) + FEPS));
            *(short4*)(KfTL + (mt * 16 + lm) * 132 + j0) = kv;
        }
    }
    __syncthreads();

    // G^T[d][m]: wave w owns d-tile w>>1, m-tiles (w&1)*4 .. +4
    {
        int dt = w >> 1, mt0 = (w & 1) * 4;
        bf16x8 va[4];
#pragma unroll
        for (int kb = 0; kb < 4; kb++)
            va[kb] = ldfragL(VTL + (dt * 16 + lm) * 132 + kb * 32 + (lq << 2));
#pragma unroll
        for (int mi = 0; mi < 4; mi++) {
            int mt = mt0 + mi;
            f32x4 acc = {0.f, 0.f, 0.f, 0.f};
#pragma unroll
            for (int kb = 0; kb < 4; kb++) {
                bf16x8 bk = ldfragL(KfTL + (mt * 16 + lm) * 132 + kb * 32 + (lq << 2));
                acc = MFMA(va[kb], bk, acc);
            }
#pragma unroll
            for (int r = 0; r < 4; r++) {
                int dd = dt * 16 + lq * 4 + r, mmo = mt * 16 + lm;
                Gt[(size_t)blk * 8192 + dd * 128 + mmo] = f2bf(acc[r]);
            }
        }
    }
    // z[m] = sum_j Kf^T[m][j]  (4 threads per m, short4-vectorized, same order)
    {
        int m = t >> 2, qd = t & 3;
        float zz = 0.f;
        const short* kp = KfTL + m * 132 + qd * 32;
#pragma unroll
        for (int j4 = 0; j4 < 8; j4++) {
            short4 v4 = *(const short4*)(kp + j4 * 4);
            zz += bf2f((unsigned short)v4.x);
            zz += bf2f((unsigned short)v4.y);
            zz += bf2f((unsigned short)v4.z);
            zz += bf2f((unsigned short)v4.w);
        }
        zz += __shfl_xor(zz, 1, 64);
        zz += __shfl_xor(zz, 2, 64);
        if (qd == 0) zs[blk * 128 + m] = zz;
    }
}

// -------- merged exclusive scans: preload 32 values, then write prefix --------
__global__ void k_scan(unsigned short* __restrict__ G, float* __restrict__ zs) {
    int blk = blockIdx.x;
    if (blk < 2048) {
        int e = blk * 256 + threadIdx.x;   // B*H*8192 = 524288 threads
        int bh = e >> 13;
        int off = e & 8191;
        unsigned short* p = G + (long)bh * NCC * 8192 + off;
        float vals[NCC];
#pragma unroll
        for (int c = 0; c < NCC; c++) vals[c] = bf2f(p[(long)c * 8192]);
        float a = 0.f;
#pragma unroll
        for (int c = 0; c < NCC; c++) { p[(long)c * 8192] = f2bf(a); a += vals[c]; }
    } else {
        int e = (blk - 2048) * 256 + threadIdx.x;   // B*H*M = 8192 threads
        int bh = e >> 7, off = e & 127;
        float* p = zs + bh * NCC * 128 + off;
        float vals[NCC];
#pragma unroll
        for (int c = 0; c < NCC; c++) vals[c] = p[c * 128];
        float a = 0.f;
#pragma unroll
        for (int c = 0; c < NCC; c++) { p[c * 128] = a; a += vals[c]; }
    }
}

// -------- MFMA attention v5.1 (8 waves): one i-tile per wave; local diagq ----
__global__ __launch_bounds__(512) void k_attn(const unsigned short* __restrict__ qg,
                                              const unsigned short* __restrict__ kg,
                                              const unsigned short* __restrict__ vg,
                                              const unsigned short* __restrict__ Gt,
                                              const float* __restrict__ zs,
                                              const float* __restrict__ diagk,
                                              const unsigned* __restrict__ kmaxU,
                                              const unsigned short* __restrict__ pb,
                                              unsigned short* __restrict__ og) {
    int blk = blockIdx.x;
    int c = blk & 31, bh = blk >> 5;
    int hh = bh & 3, b = bh >> 2;
    int t = threadIdx.x;
    int w = t >> 6, l = t & 63;
    int lm = l & 15, lq = l >> 4;
    int n0 = c * 128;
    int szl = lm & 7;
    int chA0 = (lq ^ szl) << 3;
    int chA1 = ((4 + lq) ^ szl) << 3;

    __shared__ short KfL[128 * 132];          // Kf [j][m]; later S^T [d][m]; later out-stage
    __shared__ __align__(16) short pvt[8448]; // proj [128][64] frag-major; later V^T [64][132]
    __shared__ float zb[128], dkb[128];
    short* projL = pvt;
    short* VTL = pvt;
    short* STL = KfL;
    short* outL = KfL;                        // 128x68 out-staging (fits in KfL region)

    // ---- P0: stage proj (async, pre-permuted) + smalls ----
    GL2LDS(pb + (size_t)t * 8, projL + w * 512);
    GL2LDS(pb + 4096 + (size_t)t * 8, projL + 4096 + w * 512);
    if (t < 128) {
        zb[t]  = zs[blk * 128 + t];
        dkb[t] = diagk[bh * NN + n0 + t];
    }
    float km = fdec(kmaxU[bh]);
    __syncthreads();

    // ---- P1': xqT[m][i] = proj @ Q^T for wave's i-tile w; Qf -> registers ----
    bf16x8 qfrag[4];
    float dpart;
    {
        int it = w;
        const unsigned short* qbase = qg + ((size_t)(b * NN) + n0 + it * 16 + lm) * QS + hh * DHH + (lq << 2);
        bf16x8 qb0 = ldfragG(qbase);
        bf16x8 qb1 = ldfragG(qbase + 32);
        // local diagq: same op order as old k_prep (bit-identical)
        float sq = 0.f;
#pragma unroll
        for (int j = 0; j < 8; j++) {
            float u0 = bf2f((unsigned short)qb0[j]), u1 = bf2f((unsigned short)qb1[j]);
            sq += u0 * u0 + u1 * u1;
        }
        sq += __shfl_xor(sq, 16, 64);
        sq += __shfl_xor(sq, 32, 64);
        float dq = 0.5f * DNF * DNF * sq;
        f32x4 xq[8];
#pragma unroll
        for (int mt = 0; mt < 8; mt++) {
            const short* pr_ = projL + (mt * 16 + lm) * 64;
            f32x4 acc = {0.f, 0.f, 0.f, 0.f};
            acc = MFMA(*(const bf16x8*)(pr_ + chA0), qb0, acc);
            acc = MFMA(*(const bf16x8*)(pr_ + chA1), qb1, acc);
            xq[mt] = acc;
        }
        float mv = -1e30f;
#pragma unroll
        for (int mt = 0; mt < 8; mt++)
#pragma unroll
            for (int r = 0; r < 4; r++) mv = fmaxf(mv, xq[mt][r]);
        mv = fmaxf(mv, __shfl_xor(mv, 16, 64));
        mv = fmaxf(mv, __shfl_xor(mv, 32, 64));
        float dz = 0.f;
#pragma unroll
        for (int mt = 0; mt < 8; mt++)
#pragma unroll
            for (int r = 0; r < 4; r++) {
                float e_ = RATIOF * (__expf(xq[mt][r] - dq - mv) + FEPS);
                xq[mt][r] = e_;
                dz += e_ * zb[mt * 16 + lq * 4 + r];
            }
        dpart = dz;
#pragma unroll
        for (int p = 0; p < 4; p++) qfrag[p] = pack8(xq[2 * p], xq[2 * p + 1]);
    }

    // ---- P2: Kf -> KfL[j][m] (wave's j-tile w) ----
    {
        int row0 = w * 16;
        const unsigned short* abase = kg + ((size_t)(b * NN) + n0 + row0 + lm) * QS + hh * DHH + (lq << 2);
        bf16x8 a0 = ldfragG(abase);
        bf16x8 a1 = ldfragG(abase + 32);
        int rg = row0 + lq * 4;
#pragma unroll
        for (int mt = 0; mt < 8; mt++) {
            const short* pr_ = projL + (mt * 16 + lm) * 64;
            f32x4 acc = {0.f, 0.f, 0.f, 0.f};
            acc = MFMA(a0, *(const bf16x8*)(pr_ + chA0), acc);
            acc = MFMA(a1, *(const bf16x8*)(pr_ + chA1), acc);
#pragma unroll
            for (int r = 0; r < 4; r++) {
                float e_ = RATIOF * (__expf(acc[r] - dkb[rg + r] - km) + FEPS);
                KfL[(rg + r) * 132 + mt * 16 + lm] = (short)f2bf(e_);
            }
        }
    }
    __syncthreads();   // barrier A: KfL complete; projL reads done

    // ---- V^T stage into projL region ----
    for (int e = t; e < 2048; e += 512) {
        int j = e >> 4, d4 = (e & 15) << 2;
        ushort4 vv = *(const ushort4*)(vg + ((size_t)(b * NN) + n0 + j) * QS + hh * DHH + d4);
        VTL[(d4 + 0) * 132 + j] = (short)vv.x;
        VTL[(d4 + 1) * 132 + j] = (short)vv.y;
        VTL[(d4 + 2) * 132 + j] = (short)vv.z;
        VTL[(d4 + 3) * 132 + j] = (short)vv.w;
    }

    // ---- P3': attnT[j][i] = Kf @ Qf^T (causal j<=i=w); B-frags in registers ----
    bf16x8 pfrag[4];
    float dena = 0.f;
    __builtin_amdgcn_s_setprio(1);
    {
        int it = w;
#pragma unroll
        for (int p = 0; p < 4; p++) {
            f32x4 a0 = {0.f, 0.f, 0.f, 0.f};
            f32x4 a1 = {0.f, 0.f, 0.f, 0.f};
            int jt0 = 2 * p, jt1 = 2 * p + 1;
            if (jt0 <= it) {
#pragma unroll
                for (int kb = 0; kb < 4; kb++)
                    a0 = MFMA(ldfragL(KfL + (jt0 * 16 + lm) * 132 + kb * 32 + (lq << 2)), qfrag[kb], a0);
                if (jt0 == it) {
#pragma unroll
                    for (int r = 0; r < 4; r++) if (lq * 4 + r > lm) a0[r] = 0.f;
                }
                dena += a0[0] + a0[1] + a0[2] + a0[3];
            }
            if (jt1 <= it) {
#pragma unroll
                for (int kb = 0; kb < 4; kb++)
                    a1 = MFMA(ldfragL(KfL + (jt1 * 16 + lm) * 132 + kb * 32 + (lq << 2)), qfrag[kb], a1);
                if (jt1 == it) {
#pragma unroll
                    for (int r = 0; r < 4; r++) if (lq * 4 + r > lm) a1[r] = 0.f;
                }
                dena += a1[0] + a1[1] + a1[2] + a1[3];
            }
            pfrag[p] = pack8(a0, a1);
        }
    }
    __builtin_amdgcn_s_setprio(0);
    float den = dena + dpart;
    den += __shfl_xor(den, 16, 64);
    den += __shfl_xor(den, 32, 64);
    float rden = __builtin_amdgcn_rcpf(den);
    __syncthreads();   // barrier B: KfL reads done

    // ---- S^T stage into KfL region ----
    {
        const unsigned short* gp = Gt + (size_t)blk * 8192;
        for (int e4 = t; e4 < 2048; e4 += 512) {
            int d = e4 >> 5, m4 = (e4 & 31) << 2;
            ushort4 gv = *(const ushort4*)(gp + d * 128 + m4);
            short4 sv = {(short)gv.x, (short)gv.y, (short)gv.z, (short)gv.w};
            *(short4*)(STL + d * 132 + m4) = sv;
        }
    }
    __syncthreads();   // barrier C

    // ---- P4': out^T[d][i] = V^T @ attnT + S^T @ Qf^T ----
    short4 ovr[4];
    __builtin_amdgcn_s_setprio(1);
    {
        int it = w;
        int kbmax = it >> 1;
#pragma unroll
        for (int dt = 0; dt < 4; dt++) {
            f32x4 acc = {0.f, 0.f, 0.f, 0.f};
#pragma unroll
            for (int kb = 0; kb < 4; kb++) {
                if (kb <= kbmax)
                    acc = MFMA(ldfragL(VTL + (dt * 16 + lm) * 132 + kb * 32 + (lq << 2)), pfrag[kb], acc);
            }
#pragma unroll
            for (int kb = 0; kb < 4; kb++)
                acc = MFMA(ldfragL(STL + (dt * 16 + lm) * 132 + kb * 32 + (lq << 2)), qfrag[kb], acc);
            ovr[dt] = pack4(acc[0] * rden, acc[1] * rden, acc[2] * rden, acc[3] * rden);
        }
    }
    __builtin_amdgcn_s_setprio(0);
    __syncthreads();   // barrier D: all VTL/STL reads done; reuse KfL as out-stage

    // ---- transpose-stage to LDS [i][d] (pitch 68), then PERMUTED coalesced global write ----
#pragma unroll
    for (int dt = 0; dt < 4; dt++)
        *(short4*)(outL + (w * 16 + lm) * 68 + dt * 16 + lq * 4) = ovr[dt];
    __syncthreads();   // barrier E
    for (int e = t; e < 2048; e += 512) {
        int r = e >> 4, c4 = (e & 15) << 2;       // true col group
        int afi = c4 >> 5, hlf = (c4 >> 4) & 1, lq2 = (c4 >> 2) & 3;
        int f = afi * 4 + lq2;
        int cp = ((f ^ (r & 7)) << 3) + hlf * 4;
        ushort4 xv = *(const ushort4*)(outL + r * 68 + c4);
        *(ushort4*)(og + ((size_t)(b * NN) + n0 + r) * DD + hh * 64 + cp) = xv;
    }
}

// ---------------- classifier (h bf16) ----------------
__global__ void k_cls(const unsigned short* __restrict__ h, const float* __restrict__ wc,
                      const float* __restrict__ bc, float* __restrict__ out) {
    int t = threadIdx.x;
    if (t >= BB * COUT) return;
    int b = t / COUT, c = t % COUT;
    float a = bc[c];
    for (int d = 0; d < DD; d++) a += bf2f(h[(size_t)b * NN * DD + d]) * wc[d * COUT + c];
    out[t] = a;
}

extern "C" void kernel_launch(void* const* d_in, const int* in_sizes, int n_in,
                              void* d_out, int out_size, void* d_ws, size_t ws_size,
                              hipStream_t stream) {
    const int*   x    = (const int*)d_in[0];
    const float* tok  = (const float*)d_in[1];
    const float* pos  = (const float*)d_in[2];
    const float* proj = (const float*)d_in[3];
    const float* ln1s = (const float*)d_in[4];
    const float* ln1b = (const float*)d_in[5];
    const float* wq   = (const float*)d_in[6];
    const float* wk   = (const float*)d_in[7];
    const float* wv   = (const float*)d_in[8];
    const float* wo   = (const float*)d_in[9];
    const float* bo   = (const float*)d_in[10];
    const float* ln2s = (const float*)d_in[11];
    const float* ln2b = (const float*)d_in[12];
    const float* w1   = (const float*)d_in[13];
    const float* b1   = (const float*)d_in[14];
    const float* w2   = (const float*)d_in[15];
    const float* b2   = (const float*)d_in[16];
    const float* wcls = (const float*)d_in[17];
    const float* bcls = (const float*)d_in[18];
    float* out = (float*)d_out;
    float* ws  = (float*)d_ws;

    // ---- layout (float units; SZ = 16,777,216); h bf16 ----
    const long SZ = (long)BNQ * DD;
    unsigned short* h = (unsigned short*)ws;                     // bf16 residual (SZ elems)
    unsigned short* yo = (unsigned short*)(ws + SZ);             // y / o (SZ bf16)
    unsigned short* qkv = (unsigned short*)(ws + 3 * SZ / 2);    // [65536][768] bf16
    unsigned short* G  = (unsigned short*)(ws + 3 * SZ);         // SZ bf16 (G^T per chunk)
    unsigned short* tbuf = qkv;                                  // overlays qkv+G (4SZ bf16)
    float* diagk  = ws + 7 * SZ / 2;                             // 262144
    float* diagq  = diagk + 262144;                              // 262144 (unused, layout keep)
    float* rowmax = diagq + 262144;                              // 262144 (unused, layout keep)
    float* kmax   = rowmax + 262144;                             // 64 (pad 256)
    float* zs     = kmax + 256;                                  // 262144
    unsigned short* wb = (unsigned short*)(zs + 262144);         // 3,145,728 bf16
    unsigned short* projb = wb + 3145728;                        // 32,768 bf16 (frag-major proj)
    unsigned* kmaxU = (unsigned*)kmax;

    size_t needed = (size_t)(7 * SZ / 2 + 4 * 262144 + 256) * 4 + (size_t)(3145728 + 32768) * 2;
    if (ws_size < needed) {
        k_zero<<<1, 256, 0, stream>>>(out, out_size);
        return;
    }

    unsigned short* q = qkv;            // stride QS views
    unsigned short* k = qkv + 256;
    unsigned short* v = qkv + 512;

    k_wconv<<<12416, 256, 0, stream>>>(wq, wk, wv, wo, w1, w2, proj, wb, projb);
    k_embed<<<BNQ, 256, 0, stream>>>(x, tok, pos, h);

    const size_t LW = 786432;   // per-layer stride in wb

    for (int l = 0; l < LL; l++) {
        const unsigned short* pbL = projb + (size_t)l * 8192;
        const unsigned short* wqkvT = wb + (size_t)l * LW;       // [768][256] concat q|k|v
        const unsigned short* woT = wqkvT + 3 * 65536;
        const unsigned short* w1T = woT + 65536;
        const unsigned short* w2T = w1T + 262144;
        k_ln<<<BNQ / 4, 256, 0, stream>>>(h, ln1s + l * DD, ln1b + l * DD, yo, kmaxU);
        k_gemm_mfma<false, false, false, false><<<512 * 6, 512, 0, stream>>>(yo, wqkvT, nullptr, qkv, DD, QS, 6);
        k_prep<<<BB * HH * NCC, 512, 0, stream>>>(k, pbL, diagk, kmaxU);
        k_chunkG<<<BB * HH * NCC, 512, 0, stream>>>(k, v, diagk, kmaxU, pbL, G, zs);
        k_scan<<<2080, 256, 0, stream>>>(G, zs);
        k_attn<<<BB * HH * NCC, 512, 0, stream>>>(q, k, v, G, zs, diagk, kmaxU, pbL, yo);
        k_gemm_mfma<true, true, false, false><<<512 * 2, 512, 0, stream>>>(yo, woT, bo + l * DD, h, DD, DD, 2);
        k_ln<<<BNQ / 4, 256, 0, stream>>>(h, ln2s + l * DD, ln2b + l * DD, yo, kmaxU);
        k_gemm_mfma<false, true, true, true><<<512 * 8, 512, 0, stream>>>(yo, w1T, b1 + l * 1024, tbuf, DD, 1024, 8);
        k_gemm_mfma<true, true, false, false><<<512 * 2, 512, 0, stream>>>(tbuf, w2T, b2 + l * DD, h, 1024, DD, 2);
    }
    k_cls<<<1, 256, 0, stream>>>(h, wcls, bcls, out);
}